// Round 1
// baseline (77770.978 us; speedup 1.0000x reference)
//
#include <hip/hip_runtime.h>

// Problem dims (fixed)
#define BB 64
#define SS 256
#define TT 256
#define UU 1024
#define DD 1024
#define EE 1024
#define VV 1024

#define TK 16

__device__ __forceinline__ float fast_sigmoid(float x) {
    return 1.f / (1.f + __expf(-x));
}
__device__ __forceinline__ float fast_tanh(float x) {
    // tanh(x) = 2/(1+e^{-2x}) - 1 ; saturates correctly for |x| large
    return 2.f / (1.f + __expf(-2.f * x)) - 1.f;
}

// Generic tiled fp32 GEMM over a (virtually concatenated) A of up to 3 parts.
// C[M x Ntot] = A[M x Ktot] * B[Ktot x Ntot], optionally K-split into partials.
// MODE 0: write partial tile into C + blockIdx.y*64*Ntot   (M must be 64)
// MODE 1: direct write C[r*Ntot + n]
// MODE 2: out-projection epilogue: row r = t*64+b -> C[(b*TT+t)*VV + n] + bias[n]
template <int MODE>
__global__ __launch_bounds__(256) void gemm_part(
    const float* __restrict__ A1, int k1, int s1,
    const float* __restrict__ A2, int k2, int s2,
    const float* __restrict__ A3, int s3,
    const float* __restrict__ B1, const float* __restrict__ B2, int bsplit, int ldb,
    float* __restrict__ C, int Ntot, int Ktot, int kchunk,
    const float* __restrict__ bias)
{
    __shared__ float As[64][TK];
    __shared__ float Bs[TK][64];
    const int tid  = threadIdx.x;
    const int n0   = blockIdx.x * 64;
    const int kbeg = blockIdx.y * kchunk;
    const int kend = (kbeg + kchunk < Ktot) ? (kbeg + kchunk) : Ktot;
    const int r0   = blockIdx.z * 64;

    const int j  = tid & 63;
    const int rb = tid >> 6;

    float acc[16];
#pragma unroll
    for (int i = 0; i < 16; ++i) acc[i] = 0.f;

    for (int k0 = kbeg; k0 < kend; k0 += TK) {
        // A tile: rows r0..r0+63, cols k0..k0+TK-1
        for (int e = tid; e < 64 * TK; e += 256) {
            int r  = e / TK;
            int kk = e - r * TK;
            int k  = k0 + kk;
            int gr = r0 + r;
            float v;
            if (k < k1)            v = A1[(size_t)gr * s1 + k];
            else if (k < k1 + k2)  v = A2[(size_t)gr * s2 + (k - k1)];
            else                   v = A3[(size_t)gr * s3 + (k - k1 - k2)];
            As[r][kk] = v;
        }
        // B tile
        for (int e = tid; e < TK * 64; e += 256) {
            int kk = e >> 6;
            int jj = e & 63;
            int k  = k0 + kk;
            float v = (k < bsplit) ? B1[(size_t)k * ldb + n0 + jj]
                                   : B2[(size_t)(k - bsplit) * ldb + n0 + jj];
            Bs[kk][jj] = v;
        }
        __syncthreads();
#pragma unroll
        for (int kk = 0; kk < TK; ++kk) {
            float bv = Bs[kk][j];
#pragma unroll
            for (int i = 0; i < 16; ++i)
                acc[i] = fmaf(As[rb + 4 * i][kk], bv, acc[i]);
        }
        __syncthreads();
    }

    if (MODE == 0) {
        float* Cp = C + (size_t)blockIdx.y * 64 * Ntot;
#pragma unroll
        for (int i = 0; i < 16; ++i) {
            int r = rb + 4 * i;
            Cp[(size_t)r * Ntot + n0 + j] = acc[i];
        }
    } else if (MODE == 1) {
#pragma unroll
        for (int i = 0; i < 16; ++i) {
            int r = r0 + rb + 4 * i;
            C[(size_t)r * Ntot + n0 + j] = acc[i];
        }
    } else {
#pragma unroll
        for (int i = 0; i < 16; ++i) {
            int r = r0 + rb + 4 * i;
            int b = r & 63;
            int t = r >> 6;
            C[((size_t)b * TT + t) * VV + n0 + j] = acc[i] + bias[n0 + j];
        }
    }
}

// LSTM gate nonlinearity from z partials. zp: [KC][64][4096]
__global__ __launch_bounds__(256) void gates_kernel(
    const float* __restrict__ zp, int KC,
    const float* __restrict__ b_lstm,
    const float* __restrict__ c_in,
    float* __restrict__ h_out, float* __restrict__ c_out)
{
    int idx = blockIdx.x * 256 + threadIdx.x;   // [0, 64*1024)
    int b = idx >> 10, u = idx & 1023;
    float zi = b_lstm[u];
    float zf = b_lstm[u + 1024];
    float zg = b_lstm[u + 2048];
    float zo = b_lstm[u + 3072];
    for (int kc = 0; kc < KC; ++kc) {
        const float* p = zp + (size_t)kc * 64 * 4096 + (size_t)b * 4096;
        zi += p[u];
        zf += p[u + 1024];
        zg += p[u + 2048];
        zo += p[u + 3072];
    }
    float ig = fast_sigmoid(zi);
    float fg = fast_sigmoid(zf);
    float gg = fast_tanh(zg);
    float og = fast_sigmoid(zo);
    float c  = fg * c_in[idx] + ig * gg;
    h_out[idx] = og * fast_tanh(c);
    c_out[idx] = c;
}

// Bahdanau scores: score[b][s] = sum_u v[u]*tanh(keys[b][s][u] + q[b][u]); mask.
// q assembled from qp partials in LDS. grid: (B, S/64), 256 threads (4 waves).
__global__ __launch_bounds__(256) void scores_kernel(
    const float* __restrict__ keys, const float* __restrict__ qp, int QKC,
    const float* __restrict__ v_att, const int* __restrict__ mem_len,
    float* __restrict__ scores)
{
    __shared__ float qv[1024];
    __shared__ float vv[1024];
    int b  = blockIdx.x;
    int s0 = blockIdx.y * 64;
    int tid = threadIdx.x;
    for (int e = tid; e < 1024; e += 256) {
        float a = 0.f;
        for (int kc = 0; kc < QKC; ++kc) a += qp[(size_t)kc * (BB * UU) + b * UU + e];
        qv[e] = a;
        vv[e] = v_att[e];
    }
    __syncthreads();
    int w = tid >> 6, l = tid & 63;
    int ml = mem_len[b];
    for (int i = 0; i < 16; ++i) {
        int s = s0 + w * 16 + i;
        const float* krow = keys + ((size_t)b * SS + s) * UU;
        float acc = 0.f;
#pragma unroll
        for (int m = 0; m < 16; ++m) {
            int u = l + m * 64;
            acc += fast_tanh(krow[u] + qv[u]) * vv[u];
        }
        for (int off = 32; off; off >>= 1) acc += __shfl_xor(acc, off);
        if (l == 0) scores[b * SS + s] = (s < ml) ? acc : -1e9f;
    }
}

// Softmax over S + context = align @ memory. grid: (B, D/256), 256 threads.
__global__ __launch_bounds__(256) void ctx_kernel(
    const float* __restrict__ scores, const float* __restrict__ memory,
    float* __restrict__ context)
{
    __shared__ float al[256];
    __shared__ float red[8];
    int b  = blockIdx.x;
    int d0 = blockIdx.y * 256;
    int tid = threadIdx.x;

    float sc = scores[b * SS + tid];
    float m = sc;
    for (int off = 32; off; off >>= 1) m = fmaxf(m, __shfl_xor(m, off));
    if ((tid & 63) == 0) red[tid >> 6] = m;
    __syncthreads();
    m = fmaxf(fmaxf(red[0], red[1]), fmaxf(red[2], red[3]));
    float e = __expf(sc - m);
    float sum = e;
    for (int off = 32; off; off >>= 1) sum += __shfl_xor(sum, off);
    if ((tid & 63) == 0) red[4 + (tid >> 6)] = sum;
    __syncthreads();
    sum = red[4] + red[5] + red[6] + red[7];
    al[tid] = e / sum;
    __syncthreads();

    float acc = 0.f;
    int d = d0 + tid;
    const float* mrow = memory + (size_t)b * SS * DD + d;
#pragma unroll 4
    for (int s = 0; s < SS; ++s) acc += al[s] * mrow[(size_t)s * DD];
    context[b * DD + d] = acc;
}

// out[idx] = sum_kc parts[kc][idx]   (n = 65536)
__global__ __launch_bounds__(256) void sum_parts(
    const float* __restrict__ parts, int KC, float* __restrict__ outp)
{
    int idx = blockIdx.x * 256 + threadIdx.x;
    float a = 0.f;
    for (int kc = 0; kc < KC; ++kc) a += parts[(size_t)kc * (BB * UU) + idx];
    outp[idx] = a;
}

extern "C" void kernel_launch(void* const* d_in, const int* in_sizes, int n_in,
                              void* d_out, int out_size, void* d_ws, size_t ws_size,
                              hipStream_t stream)
{
    const float* memory  = (const float*)d_in[0];
    const float* dec     = (const float*)d_in[1];
    const float* h0      = (const float*)d_in[2];
    const float* c0      = (const float*)d_in[3];
    const float* W_lstm  = (const float*)d_in[4];
    const float* U_lstm  = (const float*)d_in[5];
    const float* b_lstm  = (const float*)d_in[6];
    const float* W_mem   = (const float*)d_in[7];
    const float* W_query = (const float*)d_in[8];
    const float* v_att   = (const float*)d_in[9];
    const float* W_attn  = (const float*)d_in[10];
    const float* W_out   = (const float*)d_in[11];
    const float* b_out   = (const float*)d_in[12];
    const int*   mem_len = (const int*)d_in[13];
    float* out = (float*)d_out;

    float* ws = (float*)d_ws;
    float* keys     = ws;                      // 16,777,216 f  [B*S, U]
    float* attn_all = keys + 16777216;         // 16,777,216 f  [T][B][U]
    float* zp       = attn_all + 16777216;     //  1,572,864 f  [6][64][4096]
    float* qp       = zp + 1572864;            //    524,288 f  [8][64][1024]
    float* attnp    = qp + 524288;             //    524,288 f  [8][64][1024]
    float* scoresb  = attnp + 524288;          //     16,384 f  [64][256]
    float* hb0      = scoresb + 16384;         //     65,536 f
    float* hb1      = hb0 + 65536;
    float* cb0      = hb1 + 65536;
    float* cb1      = cb0 + 65536;
    float* ctxb     = cb1 + 65536;
    float* zerob    = ctxb + 65536;            //     65,536 f

    float* hb[2] = {hb0, hb1};
    float* cb[2] = {cb0, cb1};

    hipMemsetAsync(zerob, 0, (size_t)BB * UU * sizeof(float), stream);

    // keys = memory @ W_mem : [16384,1024] @ [1024,1024]
    gemm_part<1><<<dim3(16, 1, 256), 256, 0, stream>>>(
        memory, 1024, 1024, memory, 0, 0, memory, 0,
        W_mem, W_mem, 1024, 1024,
        keys, 1024, 1024, 1024, nullptr);

    for (int t = 0; t < TT; ++t) {
        const float* h_in = t ? hb[(t - 1) & 1] : h0;
        const float* c_in = t ? cb[(t - 1) & 1] : c0;
        const float* a_in = t ? (attn_all + (size_t)(t - 1) * (BB * UU)) : zerob;
        float* h_o = hb[t & 1];
        float* c_o = cb[t & 1];
        float* a_o = attn_all + (size_t)t * (BB * UU);

        // z partials: A = [x_t | attn_prev | h_prev], B = [W_lstm ; U_lstm]
        gemm_part<0><<<dim3(64, 6, 1), 256, 0, stream>>>(
            dec + (size_t)t * EE, 1024, TT * EE,
            a_in, 1024, 1024,
            h_in, 1024,
            W_lstm, U_lstm, 2048, 4096,
            zp, 4096, 3072, 512, nullptr);

        gates_kernel<<<256, 256, 0, stream>>>(zp, 6, b_lstm, c_in, h_o, c_o);

        // q partials: h_new @ W_query
        gemm_part<0><<<dim3(16, 8, 1), 256, 0, stream>>>(
            h_o, 1024, 1024, h_o, 0, 0, h_o, 0,
            W_query, W_query, 1024, 1024,
            qp, 1024, 1024, 128, nullptr);

        scores_kernel<<<dim3(64, 4), 256, 0, stream>>>(keys, qp, 8, v_att, mem_len, scoresb);
        ctx_kernel<<<dim3(64, 4), 256, 0, stream>>>(scoresb, memory, ctxb);

        // attn_new partials: [h_new | context] @ W_attn
        gemm_part<0><<<dim3(16, 8, 1), 256, 0, stream>>>(
            h_o, 1024, 1024, ctxb, 1024, 1024, h_o, 0,
            W_attn, W_attn, 2048, 1024,
            attnp, 1024, 2048, 256, nullptr);

        sum_parts<<<256, 256, 0, stream>>>(attnp, 8, a_o);
    }

    // out = attn_all @ W_out + b_out, scattered to [B,T,V]
    gemm_part<2><<<dim3(16, 1, 256), 256, 0, stream>>>(
        attn_all, 1024, 1024, attn_all, 0, 0, attn_all, 0,
        W_out, W_out, 1024, 1024,
        out, 1024, 1024, 1024, b_out);
}

// Round 2
// 37727.310 us; speedup vs baseline: 2.0614x; 2.0614x over previous
//
#include <hip/hip_runtime.h>

#define BB 64
#define SS 256
#define TT 256
#define UU 1024

typedef unsigned short ushort_t;
typedef __attribute__((ext_vector_type(8))) __bf16 bf16x8;
typedef __attribute__((ext_vector_type(8))) short s16x8;
typedef __attribute__((ext_vector_type(16))) float f32x16;

union PkU { s16x8 s; bf16x8 b; };

__device__ __forceinline__ ushort_t f2bf(float f) {
    unsigned u = __float_as_uint(f);
    return (ushort_t)((u + 0x7FFFu + ((u >> 16) & 1u)) >> 16);
}
__device__ __forceinline__ float bf2f(ushort_t h) {
    return __uint_as_float(((unsigned)h) << 16);
}
__device__ __forceinline__ bf16x8 ldpk(const ushort_t* p) {
    PkU u; u.s = *(const s16x8*)p; return u.b;
}
__device__ __forceinline__ void cvt8(const float* f, bf16x8& hi, bf16x8& lo) {
    PkU H, L;
#pragma unroll
    for (int e = 0; e < 8; ++e) {
        ushort_t h = f2bf(f[e]);
        H.s[e] = (short)h;
        float r = f[e] - bf2f(h);
        L.s[e] = (short)f2bf(r);
    }
    hi = H.b; lo = L.b;
}
__device__ __forceinline__ void ldcvt(const float* p, bf16x8& hi, bf16x8& lo) {
    float4 a = *(const float4*)p;
    float4 b = *(const float4*)(p + 4);
    float f[8] = {a.x, a.y, a.z, a.w, b.x, b.y, b.z, b.w};
    cvt8(f, hi, lo);
}
__device__ __forceinline__ void mfma3(f32x16& acc, bf16x8 ah, bf16x8 al, bf16x8 bh, bf16x8 bl) {
    acc = __builtin_amdgcn_mfma_f32_32x32x16_bf16(ah, bh, acc, 0, 0, 0);
    acc = __builtin_amdgcn_mfma_f32_32x32x16_bf16(ah, bl, acc, 0, 0, 0);
    acc = __builtin_amdgcn_mfma_f32_32x32x16_bf16(al, bh, acc, 0, 0, 0);
}
__device__ __forceinline__ int crow(int r, int l) {
    return (r & 3) + ((r >> 2) << 3) + ((l >> 5) << 2);
}
__device__ __forceinline__ float fast_sigmoid(float x) { return 1.f / (1.f + __expf(-x)); }
__device__ __forceinline__ float fast_tanh(float x) { return 2.f / (1.f + __expf(-2.f * x)) - 1.f; }

// ---------------- weight transpose + hi/lo split + fragment pack ----------------
// W [K][N] fp32 (row-major over k) -> pk[(s= k/16)*NT + n/32][lane][8] bf16 hi/lo
__global__ __launch_bounds__(256) void wsplit(
    const float* __restrict__ W, int ldw,
    ushort_t* __restrict__ pk_hi, ushort_t* __restrict__ pk_lo, int NT, int koff)
{
    __shared__ float tile[64][65];
    int k0 = blockIdx.x * 64, n0 = blockIdx.y * 64;
    int t = threadIdx.x;
    int r = t >> 2, cb = (t & 3) * 16;
    const float* src = W + (size_t)(k0 + r) * ldw + n0 + cb;
    float4 v0 = *(const float4*)(src);
    float4 v1 = *(const float4*)(src + 4);
    float4 v2 = *(const float4*)(src + 8);
    float4 v3 = *(const float4*)(src + 12);
    float vv[16] = {v0.x,v0.y,v0.z,v0.w, v1.x,v1.y,v1.z,v1.w, v2.x,v2.y,v2.z,v2.w, v3.x,v3.y,v3.z,v3.w};
#pragma unroll
    for (int i = 0; i < 16; ++i) tile[r][cb + i] = vv[i];
    __syncthreads();
#pragma unroll
    for (int i = 0; i < 2; ++i) {
        int gid = t + i * 256;
        int s_loc = gid >> 7, nt_loc = (gid >> 6) & 1, lane = gid & 63;
        int n_loc = nt_loc * 32 + (lane & 31);
        int kb = s_loc * 16 + (lane >> 5) * 8;
        float f[8];
#pragma unroll
        for (int e = 0; e < 8; ++e) f[e] = tile[kb + e][n_loc];
        bf16x8 hi, lo;
        cvt8(f, hi, lo);
        int s_glob = ((koff + k0) >> 4) + s_loc;
        int nt_glob = (n0 >> 5) + nt_loc;
        size_t off = ((size_t)(s_glob * NT + nt_glob) * 64 + lane) * 8;
        PkU H, L; H.b = hi; L.b = lo;
        *(s16x8*)(pk_hi + off) = H.s;
        *(s16x8*)(pk_lo + off) = L.s;
    }
}

// pack a [64][1024] fp32 matrix into A-fragment order (used once for h0)
__global__ __launch_bounds__(256) void pack64(
    const float* __restrict__ X, ushort_t* __restrict__ pk_hi, ushort_t* __restrict__ pk_lo)
{
    int gid = blockIdx.x * 256 + threadIdx.x;   // 8192 granules
    int lane = gid & 63, mt = (gid >> 6) & 1, s = gid >> 7;
    int r = mt * 32 + (lane & 31);
    int k = s * 16 + (lane >> 5) * 8;
    bf16x8 hi, lo;
    ldcvt(X + (size_t)r * 1024 + k, hi, lo);
    PkU H, L; H.b = hi; L.b = lo;
    size_t off = (size_t)gid * 8;
    *(s16x8*)(pk_hi + off) = H.s;
    *(s16x8*)(pk_lo + off) = L.s;
}

// ---------------- z-GEMM: [x_t | attn_prev | h_prev] @ [Wl;Ul], K-split partials ----
// grid 256 blocks x 256thr = 1024 wave-jobs: ntile(128) x kq(8). No LDS, no barriers.
__global__ __launch_bounds__(256) void gemm_z(
    const float* __restrict__ dec_t, const float* __restrict__ attn_prev,
    const ushort_t* __restrict__ h_hi, const ushort_t* __restrict__ h_lo,
    const ushort_t* __restrict__ Wz_hi, const ushort_t* __restrict__ Wz_lo,
    float* __restrict__ zp)
{
    int t = threadIdx.x;
    int w = t >> 6, l = t & 63;
    int job = blockIdx.x * 4 + w;
    int ntile = job >> 3, kq = job & 7;
    int n0 = ntile * 32;
    f32x16 acc[2];
#pragma unroll
    for (int i = 0; i < 2; ++i)
#pragma unroll
        for (int r = 0; r < 16; ++r) acc[i][r] = 0.f;

#pragma unroll 2
    for (int it = 0; it < 24; ++it) {
        int kg = kq * 384 + it * 16;
        bf16x8 ah[2], al[2], bh, bl;
        int src = kg >> 10;
        if (src < 2) {
            const float* base = (src == 0) ? dec_t : attn_prev;
            int stride = (src == 0) ? (TT * 1024) : 1024;
            int kl = kg & 1023;
#pragma unroll
            for (int tm = 0; tm < 2; ++tm) {
                int row = tm * 32 + (l & 31);
                ldcvt(base + (size_t)row * stride + kl + (l >> 5) * 8, ah[tm], al[tm]);
            }
        } else {
            int sl = (kg - 2048) >> 4;
#pragma unroll
            for (int tm = 0; tm < 2; ++tm) {
                size_t off = ((size_t)(sl * 2 + tm) * 64 + l) * 8;
                ah[tm] = ldpk(h_hi + off);
                al[tm] = ldpk(h_lo + off);
            }
        }
        int s = kg >> 4;
        size_t boff = ((size_t)(s * 128 + ntile) * 64 + l) * 8;
        bh = ldpk(Wz_hi + boff);
        bl = ldpk(Wz_lo + boff);
#pragma unroll
        for (int tm = 0; tm < 2; ++tm) mfma3(acc[tm], ah[tm], al[tm], bh, bl);
    }
    float* zbase = zp + (size_t)kq * (64 * 4096);
#pragma unroll
    for (int tm = 0; tm < 2; ++tm)
#pragma unroll
        for (int r = 0; r < 16; ++r) {
            int row = tm * 32 + crow(r, l);
            int col = n0 + (l & 31);
            zbase[(size_t)row * 4096 + col] = acc[tm][r];
        }
}

// ---------------- gates: reduce 8 z-partials, LSTM nonlinearity, pack h ------------
__global__ __launch_bounds__(256) void gates_k(
    const float* __restrict__ zp, const float* __restrict__ b_lstm,
    const float* __restrict__ c_in, float* __restrict__ c_out,
    ushort_t* __restrict__ h_hi, ushort_t* __restrict__ h_lo)
{
    int gid = blockIdx.x * 256 + threadIdx.x;   // 8192
    int b = gid >> 7, g8 = gid & 127;
    int u0 = g8 * 8;
    float zi[8], zf[8], zg[8], zo[8];
#pragma unroll
    for (int e = 0; e < 8; ++e) {
        zi[e] = b_lstm[u0 + e];
        zf[e] = b_lstm[1024 + u0 + e];
        zg[e] = b_lstm[2048 + u0 + e];
        zo[e] = b_lstm[3072 + u0 + e];
    }
    for (int kc = 0; kc < 8; ++kc) {
        const float* p = zp + (size_t)kc * 262144 + (size_t)b * 4096;
#pragma unroll
        for (int e = 0; e < 8; ++e) {
            zi[e] += p[u0 + e];
            zf[e] += p[1024 + u0 + e];
            zg[e] += p[2048 + u0 + e];
            zo[e] += p[3072 + u0 + e];
        }
    }
    float h[8], cn[8];
#pragma unroll
    for (int e = 0; e < 8; ++e) {
        float ig = fast_sigmoid(zi[e]);
        float fg = fast_sigmoid(zf[e]);
        float gg = fast_tanh(zg[e]);
        float og = fast_sigmoid(zo[e]);
        float c = fg * c_in[(size_t)b * 1024 + u0 + e] + ig * gg;
        cn[e] = c;
        h[e] = og * fast_tanh(c);
    }
#pragma unroll
    for (int e = 0; e < 8; ++e) c_out[(size_t)b * 1024 + u0 + e] = cn[e];
    bf16x8 hi, lo;
    cvt8(h, hi, lo);
    int s = u0 >> 4, mt = b >> 5;
    int lane = (b & 31) + ((u0 >> 3) & 1) * 32;
    size_t off = ((size_t)(s * 2 + mt) * 64 + lane) * 8;
    PkU H, L; H.b = hi; L.b = lo;
    *(s16x8*)(h_hi + off) = H.s;
    *(s16x8*)(h_lo + off) = L.s;
}

// ---------------- q / attn GEMM: packed A, in-block 4-wave K-split + LDS reduce ----
__global__ __launch_bounds__(256) void gemm_red(
    const ushort_t* __restrict__ A0h, const ushort_t* __restrict__ A0l,
    const ushort_t* __restrict__ A1h, const ushort_t* __restrict__ A1l,
    const ushort_t* __restrict__ Bh, const ushort_t* __restrict__ Bl,
    int Ktot, float* __restrict__ C)
{
    __shared__ float zbuf[64][33];
    int t = threadIdx.x;
    int w = t >> 6, l = t & 63;
    int bx = blockIdx.x;          // n-tile of 32
    int Kc = Ktot >> 2;
    int iters = Kc >> 4;
    f32x16 acc[2];
#pragma unroll
    for (int i = 0; i < 2; ++i)
#pragma unroll
        for (int r = 0; r < 16; ++r) acc[i][r] = 0.f;

#pragma unroll 2
    for (int it = 0; it < iters; ++it) {
        int kg = w * Kc + it * 16;
        const ushort_t* ph = (kg < 1024) ? A0h : A1h;
        const ushort_t* pl = (kg < 1024) ? A0l : A1l;
        int sl = (kg & 1023) >> 4;
        bf16x8 ah[2], al[2];
#pragma unroll
        for (int tm = 0; tm < 2; ++tm) {
            size_t off = ((size_t)(sl * 2 + tm) * 64 + l) * 8;
            ah[tm] = ldpk(ph + off);
            al[tm] = ldpk(pl + off);
        }
        size_t boff = ((size_t)((kg >> 4) * 32 + bx) * 64 + l) * 8;
        bf16x8 bh = ldpk(Bh + boff);
        bf16x8 bl = ldpk(Bl + boff);
#pragma unroll
        for (int tm = 0; tm < 2; ++tm) mfma3(acc[tm], ah[tm], al[tm], bh, bl);
    }
    for (int stage = 0; stage < 4; ++stage) {
        if (w == stage) {
#pragma unroll
            for (int tm = 0; tm < 2; ++tm)
#pragma unroll
                for (int r = 0; r < 16; ++r) {
                    int row = tm * 32 + crow(r, l);
                    int col = l & 31;
                    float v = acc[tm][r];
                    if (stage == 0) zbuf[row][col] = v;
                    else zbuf[row][col] += v;
                }
        }
        __syncthreads();
    }
    int c = t & 31, bq = t >> 5;
#pragma unroll
    for (int i = 0; i < 8; ++i) {
        int b = bq * 8 + i;
        C[(size_t)b * 1024 + bx * 32 + c] = zbuf[b][c];
    }
}

// ---------------- span GEMM (keys, out): wave = 64x64 tile, fp32 A cvt ------------
template <int EPI>   // 0: C[row*1024+col]; 1: out[(b*256+t)*1024+col]+bias
__global__ __launch_bounds__(256) void gemm_span(
    const float* __restrict__ A, int lda,
    const ushort_t* __restrict__ Bh, const ushort_t* __restrict__ Bl,
    float* __restrict__ C, const float* __restrict__ bias)
{
    int t = threadIdx.x;
    int w = t >> 6, l = t & 63;
    int job = blockIdx.x * 4 + w;    // 4096 jobs: 256 mt x 16 nt
    int mt = job >> 4, nt = job & 15;
    int r0 = mt * 64, n0 = nt * 64;
    f32x16 acc[4];
#pragma unroll
    for (int i = 0; i < 4; ++i)
#pragma unroll
        for (int r = 0; r < 16; ++r) acc[i][r] = 0.f;

#pragma unroll 2
    for (int it = 0; it < 64; ++it) {
        int kg = it * 16;
        bf16x8 ah[2], al[2], bh[2], bl[2];
#pragma unroll
        for (int tm = 0; tm < 2; ++tm) {
            int row = r0 + tm * 32 + (l & 31);
            ldcvt(A + (size_t)row * lda + kg + (l >> 5) * 8, ah[tm], al[tm]);
        }
#pragma unroll
        for (int tn = 0; tn < 2; ++tn) {
            size_t off = ((size_t)(it * 32 + (n0 >> 5) + tn) * 64 + l) * 8;
            bh[tn] = ldpk(Bh + off);
            bl[tn] = ldpk(Bl + off);
        }
#pragma unroll
        for (int tm = 0; tm < 2; ++tm)
#pragma unroll
            for (int tn = 0; tn < 2; ++tn)
                mfma3(acc[tm * 2 + tn], ah[tm], al[tm], bh[tn], bl[tn]);
    }
#pragma unroll
    for (int tm = 0; tm < 2; ++tm)
#pragma unroll
        for (int tn = 0; tn < 2; ++tn)
#pragma unroll
            for (int r = 0; r < 16; ++r) {
                int row = r0 + tm * 32 + crow(r, l);
                int col = n0 + tn * 32 + (l & 31);
                float v = acc[tm * 2 + tn][r];
                if (EPI == 0) {
                    C[(size_t)row * 1024 + col] = v;
                } else {
                    int tt = row >> 6, b = row & 63;
                    C[((size_t)b * 256 + tt) * 1024 + col] = v + bias[col];
                }
            }
}

// ---------------- Bahdanau scores ----------------
__global__ __launch_bounds__(256) void scores_k(
    const float* __restrict__ keys, const float* __restrict__ q,
    const float* __restrict__ v_att, const int* __restrict__ mem_len,
    float* __restrict__ scores)
{
    __shared__ float qv[1024];
    __shared__ float vv[1024];
    int b = blockIdx.x;
    int s0 = blockIdx.y * 64;
    int tid = threadIdx.x;
    for (int e = tid; e < 1024; e += 256) {
        qv[e] = q[(size_t)b * 1024 + e];
        vv[e] = v_att[e];
    }
    __syncthreads();
    int w = tid >> 6, l = tid & 63;
    int ml = mem_len[b];
    for (int i = 0; i < 16; ++i) {
        int s = s0 + w * 16 + i;
        const float* krow = keys + ((size_t)b * SS + s) * 1024;
        float acc = 0.f;
#pragma unroll
        for (int m = 0; m < 16; ++m) {
            int u = l + m * 64;
            acc += fast_tanh(krow[u] + qv[u]) * vv[u];
        }
        for (int off = 32; off; off >>= 1) acc += __shfl_xor(acc, off);
        if (l == 0) scores[b * SS + s] = (s < ml) ? acc : -1e9f;
    }
}

// ---------------- softmax + context, packed output ----------------
__global__ __launch_bounds__(256) void ctx_k(
    const float* __restrict__ scores, const float* __restrict__ memory,
    ushort_t* __restrict__ cx_hi, ushort_t* __restrict__ cx_lo)
{
    __shared__ float al[256];
    __shared__ float red[8];
    __shared__ float ctxv[256];
    int b = blockIdx.x;
    int d0 = blockIdx.y * 256;
    int tid = threadIdx.x;

    float sc = scores[b * SS + tid];
    float m = sc;
    for (int off = 32; off; off >>= 1) m = fmaxf(m, __shfl_xor(m, off));
    if ((tid & 63) == 0) red[tid >> 6] = m;
    __syncthreads();
    m = fmaxf(fmaxf(red[0], red[1]), fmaxf(red[2], red[3]));
    float e = __expf(sc - m);
    float sum = e;
    for (int off = 32; off; off >>= 1) sum += __shfl_xor(sum, off);
    if ((tid & 63) == 0) red[4 + (tid >> 6)] = sum;
    __syncthreads();
    sum = red[4] + red[5] + red[6] + red[7];
    al[tid] = e / sum;
    __syncthreads();

    float acc = 0.f;
    int d = d0 + tid;
    const float* mrow = memory + (size_t)b * SS * 1024 + d;
#pragma unroll 4
    for (int s = 0; s < SS; ++s) acc += al[s] * mrow[(size_t)s * 1024];
    ctxv[tid] = acc;
    __syncthreads();

    if (tid < 32) {
        int d8 = d0 + tid * 8;
        float f[8];
#pragma unroll
        for (int ee = 0; ee < 8; ++ee) f[ee] = ctxv[tid * 8 + ee];
        bf16x8 hi, lo;
        cvt8(f, hi, lo);
        int s = d8 >> 4, mt = b >> 5;
        int lane = (b & 31) + ((d8 >> 3) & 1) * 32;
        size_t off = ((size_t)(s * 2 + mt) * 64 + lane) * 8;
        PkU H, L; H.b = hi; L.b = lo;
        *(s16x8*)(cx_hi + off) = H.s;
        *(s16x8*)(cx_lo + off) = L.s;
    }
}

extern "C" void kernel_launch(void* const* d_in, const int* in_sizes, int n_in,
                              void* d_out, int out_size, void* d_ws, size_t ws_size,
                              hipStream_t stream)
{
    const float* memory  = (const float*)d_in[0];
    const float* dec     = (const float*)d_in[1];
    const float* h0      = (const float*)d_in[2];
    const float* c0      = (const float*)d_in[3];
    const float* W_lstm  = (const float*)d_in[4];
    const float* U_lstm  = (const float*)d_in[5];
    const float* b_lstm  = (const float*)d_in[6];
    const float* W_mem   = (const float*)d_in[7];
    const float* W_query = (const float*)d_in[8];
    const float* v_att   = (const float*)d_in[9];
    const float* W_attn  = (const float*)d_in[10];
    const float* W_out   = (const float*)d_in[11];
    const float* b_out   = (const float*)d_in[12];
    const int*   mem_len = (const int*)d_in[13];
    float* out = (float*)d_out;

    float* ws = (float*)d_ws;
    float* keys     = ws;                          // 16,777,216 f
    float* attn_all = keys + 16777216;             // 16,777,216 f
    float* zp       = attn_all + 16777216;         //  2,097,152 f
    float* zerob    = zp + 2097152;                //     65,536 f
    float* qbuf     = zerob + 65536;               //     65,536 f
    float* cbuf     = qbuf + 65536;                //     65,536 f
    float* scoresb  = cbuf + 65536;                //     16,384 f

    ushort_t* us    = (ushort_t*)(scoresb + 16384);
    ushort_t* Wz_hi = us;                          // 12,582,912 us each
    ushort_t* Wz_lo = Wz_hi + 12582912;
    ushort_t* Wq_hi = Wz_lo + 12582912;            //  1,048,576
    ushort_t* Wq_lo = Wq_hi + 1048576;
    ushort_t* Wa_hi = Wq_lo + 1048576;             //  2,097,152
    ushort_t* Wa_lo = Wa_hi + 2097152;
    ushort_t* Wo_hi = Wa_lo + 2097152;             //  1,048,576
    ushort_t* Wo_lo = Wo_hi + 1048576;
    ushort_t* Wm_hi = Wo_lo + 1048576;             //  1,048,576
    ushort_t* Wm_lo = Wm_hi + 1048576;
    ushort_t* h_hi  = Wm_lo + 1048576;             //     65,536
    ushort_t* h_lo  = h_hi + 65536;
    ushort_t* cx_hi = h_lo + 65536;
    ushort_t* cx_lo = cx_hi + 65536;

    hipMemsetAsync(zerob, 0, 65536 * sizeof(float), stream);

    // weight split+pack (per call; no static state allowed)
    wsplit<<<dim3(32, 64), 256, 0, stream>>>(W_lstm, 4096, Wz_hi, Wz_lo, 128, 0);
    wsplit<<<dim3(16, 64), 256, 0, stream>>>(U_lstm, 4096, Wz_hi, Wz_lo, 128, 2048);
    wsplit<<<dim3(16, 16), 256, 0, stream>>>(W_query, 1024, Wq_hi, Wq_lo, 32, 0);
    wsplit<<<dim3(32, 16), 256, 0, stream>>>(W_attn, 1024, Wa_hi, Wa_lo, 32, 0);
    wsplit<<<dim3(16, 16), 256, 0, stream>>>(W_out, 1024, Wo_hi, Wo_lo, 32, 0);
    wsplit<<<dim3(16, 16), 256, 0, stream>>>(W_mem, 1024, Wm_hi, Wm_lo, 32, 0);
    pack64<<<32, 256, 0, stream>>>(h0, h_hi, h_lo);

    // keys = memory @ W_mem
    gemm_span<0><<<1024, 256, 0, stream>>>(memory, 1024, Wm_hi, Wm_lo, keys, nullptr);

    for (int t = 0; t < TT; ++t) {
        const float* attn_prev = t ? (attn_all + (size_t)(t - 1) * 65536) : zerob;
        gemm_z<<<256, 256, 0, stream>>>(dec + (size_t)t * 1024, attn_prev,
                                        h_hi, h_lo, Wz_hi, Wz_lo, zp);
        gates_k<<<32, 256, 0, stream>>>(zp, b_lstm, t ? cbuf : c0, cbuf, h_hi, h_lo);
        gemm_red<<<32, 256, 0, stream>>>(h_hi, h_lo, h_hi, h_lo,
                                         Wq_hi, Wq_lo, 1024, qbuf);
        scores_k<<<dim3(64, 4), 256, 0, stream>>>(keys, qbuf, v_att, mem_len, scoresb);
        ctx_k<<<dim3(64, 4), 256, 0, stream>>>(scoresb, memory, cx_hi, cx_lo);
        gemm_red<<<32, 256, 0, stream>>>(h_hi, h_lo, cx_hi, cx_lo,
                                         Wa_hi, Wa_lo, 2048, attn_all + (size_t)t * 65536);
    }

    // out = attn_all @ W_out + b_out  (scattered to [B,T,V])
    gemm_span<1><<<1024, 256, 0, stream>>>(attn_all, 1024, Wo_hi, Wo_lo, out, b_out);
}